// Round 11
// baseline (962.588 us; speedup 1.0000x reference)
//
#include <hip/hip_runtime.h>

// ---------------------------------------------------------------------------
// CapsNet dynamic routing, fully fused, fp32.
//   x: [B=64, I=8192, N=8]   W: [I=8192, J=8, N=8, M=16]   out: [B, J=8, M=16]
//
// b_logits after t iters = dot(sum_{t'<=t} v_{t'}, u_hat); carry only
// vsum[B,J,M] between passes, recompute u_hat per pass (x,W are L3-resident).
//
// Round-11 structural insight (from 11 rounds of occupancy data): this
// scheduler runs ONE workgroup per CU at a time. Occupancy is ~36% whenever
// blocks are 1024 threads (rounds 1-2) and ~19% whenever blocks are 512
// threads (rounds 0,6,9,10) — independent of VGPR (64..128) and LDS
// (17..84 KB). Rounds 9/10 falsified the VGPR- and LDS-pool-blocker
// hypotheses. So waves/CU == blockDim/64, and 16 waves requires a
// 1024-thread block, which this toolchain hard-caps at 64 VGPRs (rounds 3-5:
// waves_per_eu, LDS-padding, launch_bounds all failed to move it).
//
// Therefore: G=2 b-blocking, designed to FIT 64 VGPRs at 1024 threads.
//   live state: s[2][4]+v[2][4]+u[2][4] = 24 + xa[2](8) + wq(4) + ptrs ~ 55.
//   (G=4 needs ~85 -> spills ~100 MB/pass at the 64 cap, rounds 3/7/8.
//    Round 1's 1024t kernel carried 4jx4m tiles = 32-float acc + 4x the W
//    reads -> DS-bound; this keeps round-9/10's lane geometry exactly.)
// Thread = (mq, j, bs): owns b in {bs, bs+32}; one W ds_read_b128 feeds
// 2b x 4m = 8 FMAs. Per-CU per-pass: DS ~4096 b128 ~10 us, VALU ~9.5 us,
// overlapped by 16 waves -> pass ~22-30 us predicted.
//
// WJ_STRIDE=136 -> wave reads 32 distinct b128 (j,mq), 2-way lane overlap,
// 8-bank j spacing: conflict-free. x from GLOBAL (32 KB chunk at NCH=16,
// L1-resident; x-in-LDS costs +8 VGPR -> spill, rounds 7/8).
// Softmax: m-dot via DPP quad_perm xor1/xor2 (VALU), j-denominator via DPP
// row_ror:4/8 + one shfl_xor(16) — identical lane layout to rounds 9/10
// (lane bits: 0-1 mq, 2-4 j, 5 bs-parity). No max-subtract (|logit| <~ 1).
// Reduce: NP=512, 256 blocks x 512 thr, 16 groups x 8-ILP (round-9 proven).
// ---------------------------------------------------------------------------

#define BB      64
#define ICAPS   8192
#define NDIM    8
#define JCAPS   8
#define MDIM    16
#define IG      8                     // i's staged per barrier
#define WJ_STRIDE 136                 // 136 mod 32 = 8 -> j-rows 8 banks apart
#define WI_STRIDE (JCAPS * WJ_STRIDE) // 1088 floats per i
#define S_ELEMS  (BB * JCAPS * MDIM)  // 8192 floats per s / vsum / out

// butterfly / rotate adds on the VALU pipe via DPP.
template <int CTRL>
__device__ __forceinline__ float dpp_xadd(float v) {
    const int p = __builtin_amdgcn_mov_dpp(__float_as_int(v), CTRL, 0xF, 0xF, true);
    return v + __int_as_float(p);
}
#define DPP_XOR1 0xB1   // quad_perm [1,0,3,2]
#define DPP_XOR2 0x4E   // quad_perm [2,3,0,1]
#define DPP_ROR4 0x124  // row_ror:4
#define DPP_ROR8 0x128  // row_ror:8

// MODE 0: uniform c = 1/8 (softmax of zero logits)
// MODE 1: c = softmax_j( dot(vsum[b,j,:], u_hat[b,i,j,:]) )
// NCH: i's per block (16 for the 512-grid path, 32 for the 256 fallback)
template <int MODE, int NCH>
__global__ __launch_bounds__(1024)
void caps_pass_kernel(
    const float* __restrict__ x, const float* __restrict__ W,
    const float* __restrict__ vsum, float* __restrict__ partial)
{
    __shared__ float Wlds[IG * WI_STRIDE];   // 34,816 B

    const int tid = threadIdx.x;             // 0..1023
    const int mq  = tid & 3;                 // m-quad (lane bits 0-1)
    const int j   = (tid >> 2) & 7;          // out-cap (lane bits 2-4)
    const int bs  = tid >> 5;                // 0..31 batch-slot; b = bs, bs+32
    const int blk = blockIdx.x;
    const int i0  = blk * NCH;

    float s[2][4];                           // [b-pair][m-quad]
    #pragma unroll
    for (int k = 0; k < 2; ++k)
        #pragma unroll
        for (int m = 0; m < 4; ++m) s[k][m] = 0.f;

    float v[2][4];
    if (MODE == 1) {
        #pragma unroll
        for (int k = 0; k < 2; ++k) {
            const float4 a = *(const float4*)
                &vsum[((bs + 32 * k) * JCAPS + j) * MDIM + mq * 4];
            v[k][0] = a.x; v[k][1] = a.y; v[k][2] = a.z; v[k][3] = a.w;
        }
    }

    // per-thread x row bases for the two b's
    const float* xp0 = x + (size_t)bs        * ICAPS * NDIM;
    const float* xp1 = x + (size_t)(bs + 32) * ICAPS * NDIM;

    for (int st = 0; st < NCH / IG; ++st) {
        // ---- stage W for IG i's (each thread: 8 contiguous floats) ----
        {
            const int iL  = tid >> 7;        // 0..7
            const int rem = tid & 127;       // 8-float chunk within the i
            const float4* src = (const float4*)(W + (size_t)(i0 + st * IG + iL) * 1024
                                                  + rem * 8);
            float4* dst = (float4*)&Wlds[iL * WI_STRIDE + (rem >> 4) * WJ_STRIDE
                                         + (rem & 15) * 8];
            dst[0] = src[0]; dst[1] = src[1];
        }
        __syncthreads();

        #pragma unroll
        for (int ii = 0; ii < IG; ++ii) {
            const int i = i0 + st * IG + ii;

            float u[2][4];
            #pragma unroll
            for (int k = 0; k < 2; ++k)
                #pragma unroll
                for (int m = 0; m < 4; ++m) u[k][m] = 0.f;
            const float* wb = &Wlds[ii * WI_STRIDE + j * WJ_STRIDE + mq * 4];

            // n-split: keep only 8 x-floats live at a time (VGPR pressure)
            {   // n = 0..3
                float4 xa[2];
                xa[0] = *(const float4*)(xp0 + (size_t)i * NDIM);
                xa[1] = *(const float4*)(xp1 + (size_t)i * NDIM);
                #pragma unroll
                for (int n = 0; n < 4; ++n) {
                    const float4 wq = *(const float4*)&wb[n * MDIM];
                    #pragma unroll
                    for (int k = 0; k < 2; ++k) {
                        const float xn = (n == 0) ? xa[k].x : (n == 1) ? xa[k].y
                                       : (n == 2) ? xa[k].z : xa[k].w;
                        u[k][0] += xn * wq.x; u[k][1] += xn * wq.y;
                        u[k][2] += xn * wq.z; u[k][3] += xn * wq.w;
                    }
                }
            }
            {   // n = 4..7
                float4 xb[2];
                xb[0] = *(const float4*)(xp0 + (size_t)i * NDIM + 4);
                xb[1] = *(const float4*)(xp1 + (size_t)i * NDIM + 4);
                #pragma unroll
                for (int n = 0; n < 4; ++n) {
                    const float4 wq = *(const float4*)&wb[(n + 4) * MDIM];
                    #pragma unroll
                    for (int k = 0; k < 2; ++k) {
                        const float xn = (n == 0) ? xb[k].x : (n == 1) ? xb[k].y
                                       : (n == 2) ? xb[k].z : xb[k].w;
                        u[k][0] += xn * wq.x; u[k][1] += xn * wq.y;
                        u[k][2] += xn * wq.z; u[k][3] += xn * wq.w;
                    }
                }
            }

            if (MODE == 0) {
                #pragma unroll
                for (int k = 0; k < 2; ++k)
                    #pragma unroll
                    for (int m = 0; m < 4; ++m) s[k][m] += u[k][m];
            } else {
                // partial logit over this m-quad (2 independent chains)
                float lp[2];
                #pragma unroll
                for (int k = 0; k < 2; ++k)
                    lp[k] = u[k][0] * v[k][0] + u[k][1] * v[k][1]
                          + u[k][2] * v[k][2] + u[k][3] * v[k][3];
                // complete m-dot across the 4 mq lanes: DPP quad_perm (VALU)
                #pragma unroll
                for (int k = 0; k < 2; ++k) lp[k] = dpp_xadd<DPP_XOR1>(lp[k]);
                #pragma unroll
                for (int k = 0; k < 2; ++k) lp[k] = dpp_xadd<DPP_XOR2>(lp[k]);
                // softmax over 8 j's: quads uniform -> row_ror:4/8 (VALU) sums
                // the 4 j's of this 16-row; one shfl_xor(16) folds the other.
                float e[2], d[2];
                #pragma unroll
                for (int k = 0; k < 2; ++k) { e[k] = __expf(lp[k]); }
                #pragma unroll
                for (int k = 0; k < 2; ++k) d[k] = dpp_xadd<DPP_ROR4>(e[k]);
                #pragma unroll
                for (int k = 0; k < 2; ++k) d[k] = dpp_xadd<DPP_ROR8>(d[k]);
                #pragma unroll
                for (int k = 0; k < 2; ++k) d[k] += __shfl_xor(d[k], 16);
                #pragma unroll
                for (int k = 0; k < 2; ++k) {
                    const float c = e[k] * __builtin_amdgcn_rcpf(d[k]);
                    #pragma unroll
                    for (int m = 0; m < 4; ++m) s[k][m] += c * u[k][m];
                }
            }
        }
        __syncthreads();
    }

    // ---- store block-partial s: partial[blk][b][j][m] (each owned once) ----
    const float sc = (MODE == 0) ? 0.125f : 1.0f;
    float* pp = partial + (size_t)blk * S_ELEMS;
    #pragma unroll
    for (int k = 0; k < 2; ++k) {
        float4 o;
        o.x = s[k][0] * sc; o.y = s[k][1] * sc;
        o.z = s[k][2] * sc; o.w = s[k][3] * sc;
        *(float4*)&pp[((bs + 32 * k) * JCAPS + j) * MDIM + mq * 4] = o;
    }
}

// Sum NPART partials -> s[b,j,m]; v = squash(s). 256 blocks x 512 threads:
// 16 groups of NPART/16 partials, 8-way ILP.
// OP 0: vsum = v (first pass, avoids memset)   OP 1: vsum += v   OP 2: out = v
template <int OP, int NPART>
__global__ __launch_bounds__(512, 1) void caps_reduce_kernel(
    const float* __restrict__ partial, float* __restrict__ vsum,
    float* __restrict__ out)
{
    constexpr int NPG = NPART / 16;     // partials per group (32 or 16)
    __shared__ float sd[512];
    const int bo  = blockIdx.x;         // 0..255, each block covers 32 outputs
    const int tid = threadIdx.x;
    const int kg  = tid >> 5;           // 0..15 partial-group
    const int tl  = tid & 31;           // output-within-block (coalesced)
    const int t   = bo * 32 + tl;       // global output index (= b*128+j*16+m)

    float a0 = 0.f, a1 = 0.f, a2 = 0.f, a3 = 0.f;
    float a4 = 0.f, a5 = 0.f, a6 = 0.f, a7 = 0.f;
    const float* p = partial + (size_t)kg * NPG * S_ELEMS + t;
    #pragma unroll
    for (int k = 0; k < NPG; k += 8) {
        a0 += p[(size_t)(k + 0) * S_ELEMS];
        a1 += p[(size_t)(k + 1) * S_ELEMS];
        a2 += p[(size_t)(k + 2) * S_ELEMS];
        a3 += p[(size_t)(k + 3) * S_ELEMS];
        a4 += p[(size_t)(k + 4) * S_ELEMS];
        a5 += p[(size_t)(k + 5) * S_ELEMS];
        a6 += p[(size_t)(k + 6) * S_ELEMS];
        a7 += p[(size_t)(k + 7) * S_ELEMS];
    }
    sd[tid] = ((a0 + a1) + (a2 + a3)) + ((a4 + a5) + (a6 + a7));
    __syncthreads();

    if (tid < 32) {
        float s = 0.f;
        #pragma unroll
        for (int q = 0; q < 16; ++q) s += sd[q * 32 + tid];   // bank = tid: clean
        // squash: sn over the 16 m's of this (b,j) — lanes grouped by 16
        float sn = s * s;
        sn += __shfl_xor(sn, 1);
        sn += __shfl_xor(sn, 2);
        sn += __shfl_xor(sn, 4);
        sn += __shfl_xor(sn, 8);
        const float vv = s * sqrtf(sn) / (1.f + sn);
        const int tt = bo * 32 + tid;
        if (OP == 2)      out[tt]   = vv;
        else if (OP == 1) vsum[tt] += vv;
        else              vsum[tt]  = vv;
    }
}

extern "C" void kernel_launch(void* const* d_in, const int* in_sizes, int n_in,
                              void* d_out, int out_size, void* d_ws, size_t ws_size,
                              hipStream_t stream)
{
    const float* x = (const float*)d_in[0];   // [64, 8192, 8]
    const float* W = (const float*)d_in[1];   // [8192, 8, 8, 16]
    float* out = (float*)d_out;               // [64, 8, 16]

    // 512-grid path needs (512+1)*8192 floats = 16.8 MB of workspace.
    const bool big = ws_size >= (size_t)(512 + 1) * S_ELEMS * sizeof(float);

    float* partial = (float*)d_ws;

    if (big) {
        float* vsum = partial + (size_t)512 * S_ELEMS;
        caps_pass_kernel<0, 16><<<512, 1024, 0, stream>>>(x, W, vsum, partial);
        caps_reduce_kernel<0, 512><<<256, 512, 0, stream>>>(partial, vsum, nullptr);
        caps_pass_kernel<1, 16><<<512, 1024, 0, stream>>>(x, W, vsum, partial);
        caps_reduce_kernel<1, 512><<<256, 512, 0, stream>>>(partial, vsum, nullptr);
        caps_pass_kernel<1, 16><<<512, 1024, 0, stream>>>(x, W, vsum, partial);
        caps_reduce_kernel<2, 512><<<256, 512, 0, stream>>>(partial, vsum, out);
    } else {
        float* vsum = partial + (size_t)256 * S_ELEMS;
        caps_pass_kernel<0, 32><<<256, 1024, 0, stream>>>(x, W, vsum, partial);
        caps_reduce_kernel<0, 256><<<256, 512, 0, stream>>>(partial, vsum, nullptr);
        caps_pass_kernel<1, 32><<<256, 1024, 0, stream>>>(x, W, vsum, partial);
        caps_reduce_kernel<1, 256><<<256, 512, 0, stream>>>(partial, vsum, nullptr);
        caps_pass_kernel<1, 32><<<256, 1024, 0, stream>>>(x, W, vsum, partial);
        caps_reduce_kernel<2, 256><<<256, 512, 0, stream>>>(partial, vsum, out);
    }
}

// Round 12
// 833.308 us; speedup vs baseline: 1.1551x; 1.1551x over previous
//
#include <hip/hip_runtime.h>

// ---------------------------------------------------------------------------
// CapsNet dynamic routing, fully fused, fp32.
//   x: [B=64, I=8192, N=8]   W: [I=8192, J=8, N=8, M=16]   out: [B, J=8, M=16]
//
// b_logits after t iters = dot(sum_{t'<=t} v_{t'}, u_hat); carry only
// vsum[B,J,M] between passes, recompute u_hat per pass (x,W are L3-resident).
//
// HW facts established over rounds 0-11 (do not re-litigate):
//   * Scheduler runs ONE workgroup per CU regardless of VGPR/LDS (falsified:
//     VGPR-cap r9, LDS-pool r10). waves/CU == blockDim/64.
//   * 1024t blocks are hard-capped at 64 VGPR -> G>=2 spills catastrophically
//     (r3-5, r7-8, r11: 50 MB-1.4 GB/pass scratch). 1024t is closed.
//   * 512t + __launch_bounds__(512,1): allocator behaves (r0: 100, r6/9: 120).
//     At 1 WG/CU = 2 waves/SIMD the real budget is 256 VGPR/wave -> ~130
//     regs of headroom that r9's 45-us pass (VALUBusy 34%) never used.
//
// Round-12: spend that headroom on in-thread latency hiding (the only
// coverage mechanism at 2 waves/SIMD):
//   * x software-pipeline: load i+1's 8 float4 rows while computing i.
//   * W LDS double-buffer (2 x 34,816 B) + async-stage split: stage st+1
//     global loads issue BEFORE compute, ds_writes AFTER -> staging hidden,
//     one barrier per stage.
//   * float4 reduce: 256 x 512, 64 groups, two-level LDS tree (~4 us vs ~16).
// Layout (proven): grid 512/NCH=16, thread=(bq,j,mq) owns b in {bq,+16,+32,
// +48}; one W ds_read_b128 feeds 4b x 4m = 16 FMAs. WJ_STRIDE=136 -> 2-way
// banks (free). Softmax: DPP quad_perm xor1/2 m-dot, row_ror:4/8 + one
// shfl_xor(16) j-denominator. No max-subtract (|logit| <~ 1).
// ---------------------------------------------------------------------------

#define BB      64
#define ICAPS   8192
#define NDIM    8
#define JCAPS   8
#define MDIM    16
#define IG      8                     // i's staged per barrier
#define WJ_STRIDE 136                 // 136 mod 32 = 8 -> j-rows 8 banks apart
#define WI_STRIDE (JCAPS * WJ_STRIDE) // 1088 floats per i
#define S_ELEMS  (BB * JCAPS * MDIM)  // 8192 floats per s / vsum / out

// butterfly / rotate adds on the VALU pipe via DPP.
template <int CTRL>
__device__ __forceinline__ float dpp_xadd(float v) {
    const int p = __builtin_amdgcn_mov_dpp(__float_as_int(v), CTRL, 0xF, 0xF, true);
    return v + __int_as_float(p);
}
#define DPP_XOR1 0xB1   // quad_perm [1,0,3,2]
#define DPP_XOR2 0x4E   // quad_perm [2,3,0,1]
#define DPP_ROR4 0x124  // row_ror:4
#define DPP_ROR8 0x128  // row_ror:8

__device__ __forceinline__ float4 f4add(float4 a, float4 b) {
    float4 r; r.x = a.x + b.x; r.y = a.y + b.y; r.z = a.z + b.z; r.w = a.w + b.w;
    return r;
}

// MODE 0: uniform c = 1/8 (softmax of zero logits)
// MODE 1: c = softmax_j( dot(vsum[b,j,:], u_hat[b,i,j,:]) )
// NCH: i's per block (16 for the 512-grid path, 32 for the 256 fallback)
template <int MODE, int NCH>
__global__ __launch_bounds__(512, 1)
void caps_pass_kernel(
    const float* __restrict__ x, const float* __restrict__ W,
    const float* __restrict__ vsum, float* __restrict__ partial)
{
    constexpr int NST = NCH / IG;
    __shared__ float Wlds[2][IG * WI_STRIDE];   // 69,632 B (1 WG/CU anyway)

    const int tid = threadIdx.x;             // 0..511
    const int mq  = tid & 3;                 // m-quad (lane bits 0-1)
    const int j   = (tid >> 2) & 7;          // out-cap (lane bits 2-4)
    const int bq  = tid >> 5;                // 0..15 batch-quad base
    const int blk = blockIdx.x;
    const int i0  = blk * NCH;

    // staging geometry: thread moves 16 contiguous floats of one i per stage
    const int iL  = tid >> 6;                // 0..7
    const int rem = tid & 63;
    const size_t wsrc0 = (size_t)(i0 + iL) * 1024 + rem * 16;
    const int wdst_off = iL * WI_STRIDE + (rem >> 3) * WJ_STRIDE + (rem & 7) * 16;

    float s[4][4];                           // [b-quad][m-quad]
    #pragma unroll
    for (int k = 0; k < 4; ++k)
        #pragma unroll
        for (int m = 0; m < 4; ++m) s[k][m] = 0.f;

    float v[4][4];
    if (MODE == 1) {
        #pragma unroll
        for (int k = 0; k < 4; ++k) {
            const float4 a = *(const float4*)
                &vsum[((bq + 16 * k) * JCAPS + j) * MDIM + mq * 4];
            v[k][0] = a.x; v[k][1] = a.y; v[k][2] = a.z; v[k][3] = a.w;
        }
    }

    // ---- prologue: stage st=0 into buf0; preload x row for i0 ----
    {
        const float4* src = (const float4*)(W + wsrc0);
        float4* dst = (float4*)&Wlds[0][wdst_off];
        dst[0] = src[0]; dst[1] = src[1]; dst[2] = src[2]; dst[3] = src[3];
    }
    float4 xc[4][2];
    #pragma unroll
    for (int k = 0; k < 4; ++k) {
        const size_t xo = ((size_t)(bq + 16 * k) * ICAPS + i0) * NDIM;
        xc[k][0] = *(const float4*)&x[xo];
        xc[k][1] = *(const float4*)&x[xo + 4];
    }
    __syncthreads();

    #pragma unroll
    for (int st = 0; st < NST; ++st) {
        const int cur = st & 1;

        // async-stage split: issue next stage's W loads BEFORE compute
        float4 p0, p1, p2, p3;
        if (st + 1 < NST) {
            const float4* src = (const float4*)(W + wsrc0 + (size_t)(st + 1) * IG * 1024);
            p0 = src[0]; p1 = src[1]; p2 = src[2]; p3 = src[3];
        }

        #pragma unroll
        for (int ii = 0; ii < IG; ++ii) {
            const int i = i0 + st * IG + ii;
            // x pipeline: load i+1 (clamped in-block) while computing i
            const int inx = (st * IG + ii + 1 < NCH) ? (i + 1) : i0;
            float4 xn[4][2];
            #pragma unroll
            for (int k = 0; k < 4; ++k) {
                const size_t xo = ((size_t)(bq + 16 * k) * ICAPS + inx) * NDIM;
                xn[k][0] = *(const float4*)&x[xo];
                xn[k][1] = *(const float4*)&x[xo + 4];
            }

            // u_hat fragment from current x regs + LDS W
            float u[4][4];
            #pragma unroll
            for (int k = 0; k < 4; ++k)
                #pragma unroll
                for (int m = 0; m < 4; ++m) u[k][m] = 0.f;
            const float* wb = &Wlds[cur][ii * WI_STRIDE + j * WJ_STRIDE + mq * 4];
            #pragma unroll
            for (int n = 0; n < 8; ++n) {
                const float4 wq = *(const float4*)&wb[n * MDIM];
                #pragma unroll
                for (int k = 0; k < 4; ++k) {
                    const float4 xh = xc[k][n >> 2];        // const idx (unrolled)
                    const float xv = ((n & 3) == 0) ? xh.x : ((n & 3) == 1) ? xh.y
                                   : ((n & 3) == 2) ? xh.z : xh.w;
                    u[k][0] += xv * wq.x; u[k][1] += xv * wq.y;
                    u[k][2] += xv * wq.z; u[k][3] += xv * wq.w;
                }
            }

            if (MODE == 0) {
                #pragma unroll
                for (int k = 0; k < 4; ++k)
                    #pragma unroll
                    for (int m = 0; m < 4; ++m) s[k][m] += u[k][m];
            } else {
                // partial logit over this m-quad (4 independent chains)
                float lp[4];
                #pragma unroll
                for (int k = 0; k < 4; ++k)
                    lp[k] = u[k][0] * v[k][0] + u[k][1] * v[k][1]
                          + u[k][2] * v[k][2] + u[k][3] * v[k][3];
                // complete m-dot across the 4 mq lanes: DPP quad_perm (VALU)
                #pragma unroll
                for (int k = 0; k < 4; ++k) lp[k] = dpp_xadd<DPP_XOR1>(lp[k]);
                #pragma unroll
                for (int k = 0; k < 4; ++k) lp[k] = dpp_xadd<DPP_XOR2>(lp[k]);
                // softmax over 8 j's: quads uniform -> row_ror:4/8 (VALU) sums
                // the 4 j's of this 16-row; one shfl_xor(16) folds the other.
                float e[4], d[4];
                #pragma unroll
                for (int k = 0; k < 4; ++k) { e[k] = __expf(lp[k]); }
                #pragma unroll
                for (int k = 0; k < 4; ++k) d[k] = dpp_xadd<DPP_ROR4>(e[k]);
                #pragma unroll
                for (int k = 0; k < 4; ++k) d[k] = dpp_xadd<DPP_ROR8>(d[k]);
                #pragma unroll
                for (int k = 0; k < 4; ++k) d[k] += __shfl_xor(d[k], 16);
                #pragma unroll
                for (int k = 0; k < 4; ++k) {
                    const float c = e[k] * __builtin_amdgcn_rcpf(d[k]);
                    #pragma unroll
                    for (int m = 0; m < 4; ++m) s[k][m] += c * u[k][m];
                }
            }

            // advance x pipeline (unrolled loop -> pure register renaming)
            #pragma unroll
            for (int k = 0; k < 4; ++k) { xc[k][0] = xn[k][0]; xc[k][1] = xn[k][1]; }
        }

        // async-stage split: land next stage's W into the other buffer
        if (st + 1 < NST) {
            float4* dst = (float4*)&Wlds[cur ^ 1][wdst_off];
            dst[0] = p0; dst[1] = p1; dst[2] = p2; dst[3] = p3;
        }
        __syncthreads();
    }

    // ---- store block-partial s: partial[blk][b][j][m] (each owned once) ----
    const float sc = (MODE == 0) ? 0.125f : 1.0f;
    float* pp = partial + (size_t)blk * S_ELEMS;
    #pragma unroll
    for (int k = 0; k < 4; ++k) {
        float4 o;
        o.x = s[k][0] * sc; o.y = s[k][1] * sc;
        o.z = s[k][2] * sc; o.w = s[k][3] * sc;
        *(float4*)&pp[((bq + 16 * k) * JCAPS + j) * MDIM + mq * 4] = o;
    }
}

// Sum NPART partials -> s[b,j,m]; v = squash(s). float4 throughout.
// 256 blocks x 512 threads: block covers 8 float4-outputs (2 (b,j) rows);
// 64 groups of NPG partials each, then two-level LDS tree.
// OP 0: vsum = v (first pass, avoids memset)   OP 1: vsum += v   OP 2: out = v
template <int OP, int NPART>
__global__ __launch_bounds__(512, 1) void caps_reduce_kernel(
    const float* __restrict__ partial, float* __restrict__ vsum,
    float* __restrict__ out)
{
    constexpr int NPG = NPART / 64;     // partials per group (8 or 4)
    constexpr int S4  = S_ELEMS / 4;    // 2048 float4 per partial
    __shared__ float4 sd4[512];         // 8 KB
    const int bo  = blockIdx.x;         // 0..255
    const int tid = threadIdx.x;
    const int fq  = tid & 7;            // float4-output within block
    const int kg  = tid >> 3;           // 0..63 partial-group
    const int t4  = bo * 8 + fq;        // global float4 output index (0..2047)
    const float4* p4 = (const float4*)partial;

    float4 a0 = make_float4(0.f, 0.f, 0.f, 0.f);
    float4 a1 = make_float4(0.f, 0.f, 0.f, 0.f);
    #pragma unroll
    for (int k = 0; k < NPG; k += 2) {
        a0 = f4add(a0, p4[(size_t)(kg * NPG + k)     * S4 + t4]);
        a1 = f4add(a1, p4[(size_t)(kg * NPG + k + 1) * S4 + t4]);
    }
    sd4[tid] = f4add(a0, a1);           // tid == kg*8 + fq
    __syncthreads();

    if (tid < 8) {
        float4 r0 = make_float4(0.f, 0.f, 0.f, 0.f);
        float4 r1 = make_float4(0.f, 0.f, 0.f, 0.f);
        #pragma unroll
        for (int g = 0; g < 64; g += 2) {
            r0 = f4add(r0, sd4[(g    ) * 8 + tid]);
            r1 = f4add(r1, sd4[(g + 1) * 8 + tid]);
        }
        const float4 r = f4add(r0, r1);
        // squash: lanes 0-3 = row bo*2, lanes 4-7 = row bo*2+1 (16 m's each)
        float sn = r.x * r.x + r.y * r.y + r.z * r.z + r.w * r.w;
        sn += __shfl_xor(sn, 1);
        sn += __shfl_xor(sn, 2);
        const float f = sqrtf(sn) / (1.f + sn);
        float4 vv;
        vv.x = r.x * f; vv.y = r.y * f; vv.z = r.z * f; vv.w = r.w * f;
        float4* vs4 = (float4*)vsum;
        if (OP == 2)      ((float4*)out)[t4] = vv;
        else if (OP == 1) vs4[t4] = f4add(vs4[t4], vv);
        else              vs4[t4] = vv;
    }
}

extern "C" void kernel_launch(void* const* d_in, const int* in_sizes, int n_in,
                              void* d_out, int out_size, void* d_ws, size_t ws_size,
                              hipStream_t stream)
{
    const float* x = (const float*)d_in[0];   // [64, 8192, 8]
    const float* W = (const float*)d_in[1];   // [8192, 8, 8, 16]
    float* out = (float*)d_out;               // [64, 8, 16]

    // 512-grid path needs (512+1)*8192 floats = 16.8 MB of workspace.
    const bool big = ws_size >= (size_t)(512 + 1) * S_ELEMS * sizeof(float);

    float* partial = (float*)d_ws;

    if (big) {
        float* vsum = partial + (size_t)512 * S_ELEMS;
        caps_pass_kernel<0, 16><<<512, 512, 0, stream>>>(x, W, vsum, partial);
        caps_reduce_kernel<0, 512><<<256, 512, 0, stream>>>(partial, vsum, nullptr);
        caps_pass_kernel<1, 16><<<512, 512, 0, stream>>>(x, W, vsum, partial);
        caps_reduce_kernel<1, 512><<<256, 512, 0, stream>>>(partial, vsum, nullptr);
        caps_pass_kernel<1, 16><<<512, 512, 0, stream>>>(x, W, vsum, partial);
        caps_reduce_kernel<2, 512><<<256, 512, 0, stream>>>(partial, vsum, out);
    } else {
        float* vsum = partial + (size_t)256 * S_ELEMS;
        caps_pass_kernel<0, 32><<<256, 512, 0, stream>>>(x, W, vsum, partial);
        caps_reduce_kernel<0, 256><<<256, 512, 0, stream>>>(partial, vsum, nullptr);
        caps_pass_kernel<1, 32><<<256, 512, 0, stream>>>(x, W, vsum, partial);
        caps_reduce_kernel<1, 256><<<256, 512, 0, stream>>>(partial, vsum, nullptr);
        caps_pass_kernel<1, 32><<<256, 512, 0, stream>>>(x, W, vsum, partial);
        caps_reduce_kernel<2, 256><<<256, 512, 0, stream>>>(partial, vsum, out);
    }
}

// Round 13
// 675.878 us; speedup vs baseline: 1.4242x; 1.2329x over previous
//
#include <hip/hip_runtime.h>

// ---------------------------------------------------------------------------
// CapsNet dynamic routing, fully fused, fp32.
//   x: [B=64, I=8192, N=8]   W: [I=8192, J=8, N=8, M=16]   out: [B, J=8, M=16]
//
// b_logits after t iters = dot(sum_{t'<=t} v_{t'}, u_hat); carry only
// vsum[B,J,M] between passes, recompute u_hat per pass (x,W are L3-resident).
//
// HW facts established over rounds 0-12 (do not re-litigate):
//   * Scheduler runs ONE workgroup per CU regardless of VGPR/LDS (r9/r10).
//     waves/CU == blockDim/64. 512t -> 2 waves/SIMD.
//   * Allocator VGPR ceiling is 128 at 512t (observed 100/120/128, never
//     more — r12's "256 budget" hypothesis falsified: 528 MB/pass spill).
//     1024t is capped at 64 -> any G>=2 spills (r3-5, r7-8, r11). Closed.
//   * r9 body (G=4, x from global, n-split halves): VGPR=120 zero-spill,
//     45.2 us/pass, VALUBusy 34% -> stalled on per-i global x loads.
//
// Round-13: remove vmcnt from the loop at ZERO register cost. Stage the
// block's x-chunk (64b x NCH i x 32 B) into LDS ONCE before the main loop
// (32 KB at NCH=16). Inner loop = r9 verbatim except x reads come from LDS:
//   * x addressing: one 32-bit LDS base + compile-time offsets (replaces
//     four 64-bit global pointers) -> register pressure drops, not rises.
//   * x ds_reads are pure broadcast (lanes 0-31 share one bq -> one addr):
//     conflict-free by construction.
//   * DS pipe: 16 b128/thread/i ~ 10 us/CU/pass, still under the ~15 us
//     VALU floor; lgkmcnt scheduling across the unrolled i's is what the
//     compiler does well (unlike vmcnt).
// (r7/r8's x-LDS failed for a different reason: PER-STAGE staging kept live
// staging registers + hoisted W float4s -> 128-cap spill. One-shot staging
// outside the loop has no in-loop footprint.)
//
// Layout (proven): grid 512/NCH=16, thread=(bq,j,mq) owns b in {bq,+16,+32,
// +48}; one W ds_read_b128 feeds 4b x 4m = 16 FMAs. WJ_STRIDE=136 -> 2-way
// banks (free). Softmax: DPP quad_perm xor1/2 m-dot, row_ror:4/8 + one
// shfl_xor(16) j-denominator. No max-subtract (|logit| <~ 1).
// Reduce: float4, 256 x 512, 64 groups, two-level LDS tree; OP0 writes vsum.
// ---------------------------------------------------------------------------

#define BB      64
#define ICAPS   8192
#define NDIM    8
#define JCAPS   8
#define MDIM    16
#define IG      8                     // i's staged per barrier (W)
#define WJ_STRIDE 136                 // 136 mod 32 = 8 -> j-rows 8 banks apart
#define WI_STRIDE (JCAPS * WJ_STRIDE) // 1088 floats per i
#define S_ELEMS  (BB * JCAPS * MDIM)  // 8192 floats per s / vsum / out

// butterfly / rotate adds on the VALU pipe via DPP.
template <int CTRL>
__device__ __forceinline__ float dpp_xadd(float v) {
    const int p = __builtin_amdgcn_mov_dpp(__float_as_int(v), CTRL, 0xF, 0xF, true);
    return v + __int_as_float(p);
}
#define DPP_XOR1 0xB1   // quad_perm [1,0,3,2]
#define DPP_XOR2 0x4E   // quad_perm [2,3,0,1]
#define DPP_ROR4 0x124  // row_ror:4
#define DPP_ROR8 0x128  // row_ror:8

__device__ __forceinline__ float4 f4add(float4 a, float4 b) {
    float4 r; r.x = a.x + b.x; r.y = a.y + b.y; r.z = a.z + b.z; r.w = a.w + b.w;
    return r;
}

// MODE 0: uniform c = 1/8 (softmax of zero logits)
// MODE 1: c = softmax_j( dot(vsum[b,j,:], u_hat[b,i,j,:]) )
// NCH: i's per block (16 for the 512-grid path, 32 for the 256 fallback)
template <int MODE, int NCH>
__global__ __launch_bounds__(512, 1)
void caps_pass_kernel(
    const float* __restrict__ x, const float* __restrict__ W,
    const float* __restrict__ vsum, float* __restrict__ partial)
{
    constexpr int NST  = NCH / IG;
    constexpr int XSTR = NCH * NDIM + 4;     // x row stride in LDS (pad)
    __shared__ float Wlds[IG * WI_STRIDE];   // 34,816 B
    __shared__ float Xlds[BB * XSTR];        // 33,792 B @NCH=16 (66,560 @32)

    const int tid = threadIdx.x;             // 0..511
    const int mq  = tid & 3;                 // m-quad (lane bits 0-1)
    const int j   = (tid >> 2) & 7;          // out-cap (lane bits 2-4)
    const int bq  = tid >> 5;                // 0..15 batch-quad base
    const int blk = blockIdx.x;
    const int i0  = blk * NCH;

    float s[4][4];                           // [b-quad][m-quad]
    #pragma unroll
    for (int k = 0; k < 4; ++k)
        #pragma unroll
        for (int m = 0; m < 4; ++m) s[k][m] = 0.f;

    float v[4][4];
    if (MODE == 1) {
        #pragma unroll
        for (int k = 0; k < 4; ++k) {
            const float4 a = *(const float4*)
                &vsum[((bq + 16 * k) * JCAPS + j) * MDIM + mq * 4];
            v[k][0] = a.x; v[k][1] = a.y; v[k][2] = a.z; v[k][3] = a.w;
        }
    }

    // ---- stage x ONCE: all 64 b-rows of this block's i-chunk (coalesced) ----
    {
        constexpr int F = NCH * NDIM / 4 / 8;   // float4 per thread (4 or 8)
        const int tb = tid >> 3;                // 0..63 batch row
        const int tc = tid & 7;                 // chunk-of-row
        const float4* src = (const float4*)(x + (size_t)tb * ICAPS * NDIM
                                              + (size_t)i0 * NDIM) + tc * F;
        float4* dst = (float4*)&Xlds[tb * XSTR] + tc * F;
        #pragma unroll
        for (int f = 0; f < F; ++f) dst[f] = src[f];
    }
    const float* xB = &Xlds[bq * XSTR];      // single 32-bit base register

    #pragma unroll
    for (int st = 0; st < NST; ++st) {
        // ---- stage W for IG i's (each thread: 16 contiguous floats) ----
        {
            const int iL  = tid >> 6;        // 0..7
            const int rem = tid & 63;        // 16-float chunk within the i
            const float4* src = (const float4*)(W + (size_t)(i0 + st * IG + iL) * 1024
                                                  + rem * 16);
            float4* dst = (float4*)&Wlds[iL * WI_STRIDE + (rem >> 3) * WJ_STRIDE
                                         + (rem & 7) * 16];
            dst[0] = src[0]; dst[1] = src[1]; dst[2] = src[2]; dst[3] = src[3];
        }
        __syncthreads();   // covers x staging on st=0 as well

        #pragma unroll
        for (int ii = 0; ii < IG; ++ii) {
            const int i = st * IG + ii;      // block-local i (compile-time)

            float u[4][4];
            #pragma unroll
            for (int k = 0; k < 4; ++k)
                #pragma unroll
                for (int m = 0; m < 4; ++m) u[k][m] = 0.f;
            const float* wb = &Wlds[ii * WI_STRIDE + j * WJ_STRIDE + mq * 4];

            // n-split halves (r9 structure); x now from LDS, broadcast reads
            {   // n = 0..3
                float4 xa[4];
                #pragma unroll
                for (int k = 0; k < 4; ++k)
                    xa[k] = *(const float4*)(xB + 16 * k * XSTR + i * NDIM);
                #pragma unroll
                for (int n = 0; n < 4; ++n) {
                    const float4 wq = *(const float4*)&wb[n * MDIM];
                    #pragma unroll
                    for (int k = 0; k < 4; ++k) {
                        const float xn = (n == 0) ? xa[k].x : (n == 1) ? xa[k].y
                                       : (n == 2) ? xa[k].z : xa[k].w;
                        u[k][0] += xn * wq.x; u[k][1] += xn * wq.y;
                        u[k][2] += xn * wq.z; u[k][3] += xn * wq.w;
                    }
                }
            }
            {   // n = 4..7
                float4 xb[4];
                #pragma unroll
                for (int k = 0; k < 4; ++k)
                    xb[k] = *(const float4*)(xB + 16 * k * XSTR + i * NDIM + 4);
                #pragma unroll
                for (int n = 0; n < 4; ++n) {
                    const float4 wq = *(const float4*)&wb[(n + 4) * MDIM];
                    #pragma unroll
                    for (int k = 0; k < 4; ++k) {
                        const float xn = (n == 0) ? xb[k].x : (n == 1) ? xb[k].y
                                       : (n == 2) ? xb[k].z : xb[k].w;
                        u[k][0] += xn * wq.x; u[k][1] += xn * wq.y;
                        u[k][2] += xn * wq.z; u[k][3] += xn * wq.w;
                    }
                }
            }

            if (MODE == 0) {
                #pragma unroll
                for (int k = 0; k < 4; ++k)
                    #pragma unroll
                    for (int m = 0; m < 4; ++m) s[k][m] += u[k][m];
            } else {
                // partial logit over this m-quad (4 independent chains)
                float lp[4];
                #pragma unroll
                for (int k = 0; k < 4; ++k)
                    lp[k] = u[k][0] * v[k][0] + u[k][1] * v[k][1]
                          + u[k][2] * v[k][2] + u[k][3] * v[k][3];
                // complete m-dot across the 4 mq lanes: DPP quad_perm (VALU)
                #pragma unroll
                for (int k = 0; k < 4; ++k) lp[k] = dpp_xadd<DPP_XOR1>(lp[k]);
                #pragma unroll
                for (int k = 0; k < 4; ++k) lp[k] = dpp_xadd<DPP_XOR2>(lp[k]);
                // softmax over 8 j's: quads uniform -> row_ror:4/8 (VALU) sums
                // the 4 j's of this 16-row; one shfl_xor(16) folds the other.
                float e[4], d[4];
                #pragma unroll
                for (int k = 0; k < 4; ++k) { e[k] = __expf(lp[k]); }
                #pragma unroll
                for (int k = 0; k < 4; ++k) d[k] = dpp_xadd<DPP_ROR4>(e[k]);
                #pragma unroll
                for (int k = 0; k < 4; ++k) d[k] = dpp_xadd<DPP_ROR8>(d[k]);
                #pragma unroll
                for (int k = 0; k < 4; ++k) d[k] += __shfl_xor(d[k], 16);
                #pragma unroll
                for (int k = 0; k < 4; ++k) {
                    const float c = e[k] * __builtin_amdgcn_rcpf(d[k]);
                    #pragma unroll
                    for (int m = 0; m < 4; ++m) s[k][m] += c * u[k][m];
                }
            }
        }
        __syncthreads();
    }

    // ---- store block-partial s: partial[blk][b][j][m] (each owned once) ----
    const float sc = (MODE == 0) ? 0.125f : 1.0f;
    float* pp = partial + (size_t)blk * S_ELEMS;
    #pragma unroll
    for (int k = 0; k < 4; ++k) {
        float4 o;
        o.x = s[k][0] * sc; o.y = s[k][1] * sc;
        o.z = s[k][2] * sc; o.w = s[k][3] * sc;
        *(float4*)&pp[((bq + 16 * k) * JCAPS + j) * MDIM + mq * 4] = o;
    }
}

// Sum NPART partials -> s[b,j,m]; v = squash(s). float4 throughout.
// 256 blocks x 512 threads: block covers 8 float4-outputs (2 (b,j) rows);
// 64 groups of NPG partials each, then two-level LDS tree.
// OP 0: vsum = v (first pass, avoids memset)   OP 1: vsum += v   OP 2: out = v
template <int OP, int NPART>
__global__ __launch_bounds__(512, 1) void caps_reduce_kernel(
    const float* __restrict__ partial, float* __restrict__ vsum,
    float* __restrict__ out)
{
    constexpr int NPG = NPART / 64;     // partials per group (8 or 4)
    constexpr int S4  = S_ELEMS / 4;    // 2048 float4 per partial
    __shared__ float4 sd4[512];         // 8 KB
    const int bo  = blockIdx.x;         // 0..255
    const int tid = threadIdx.x;
    const int fq  = tid & 7;            // float4-output within block
    const int kg  = tid >> 3;           // 0..63 partial-group
    const int t4  = bo * 8 + fq;        // global float4 output index (0..2047)
    const float4* p4 = (const float4*)partial;

    float4 a0 = make_float4(0.f, 0.f, 0.f, 0.f);
    float4 a1 = make_float4(0.f, 0.f, 0.f, 0.f);
    #pragma unroll
    for (int k = 0; k < NPG; k += 2) {
        a0 = f4add(a0, p4[(size_t)(kg * NPG + k)     * S4 + t4]);
        a1 = f4add(a1, p4[(size_t)(kg * NPG + k + 1) * S4 + t4]);
    }
    sd4[tid] = f4add(a0, a1);           // tid == kg*8 + fq
    __syncthreads();

    if (tid < 8) {
        float4 r0 = make_float4(0.f, 0.f, 0.f, 0.f);
        float4 r1 = make_float4(0.f, 0.f, 0.f, 0.f);
        #pragma unroll
        for (int g = 0; g < 64; g += 2) {
            r0 = f4add(r0, sd4[(g    ) * 8 + tid]);
            r1 = f4add(r1, sd4[(g + 1) * 8 + tid]);
        }
        const float4 r = f4add(r0, r1);
        // squash: lanes 0-3 = row bo*2, lanes 4-7 = row bo*2+1 (16 m's each)
        float sn = r.x * r.x + r.y * r.y + r.z * r.z + r.w * r.w;
        sn += __shfl_xor(sn, 1);
        sn += __shfl_xor(sn, 2);
        const float f = sqrtf(sn) / (1.f + sn);
        float4 vv;
        vv.x = r.x * f; vv.y = r.y * f; vv.z = r.z * f; vv.w = r.w * f;
        float4* vs4 = (float4*)vsum;
        if (OP == 2)      ((float4*)out)[t4] = vv;
        else if (OP == 1) vs4[t4] = f4add(vs4[t4], vv);
        else              vs4[t4] = vv;
    }
}

extern "C" void kernel_launch(void* const* d_in, const int* in_sizes, int n_in,
                              void* d_out, int out_size, void* d_ws, size_t ws_size,
                              hipStream_t stream)
{
    const float* x = (const float*)d_in[0];   // [64, 8192, 8]
    const float* W = (const float*)d_in[1];   // [8192, 8, 8, 16]
    float* out = (float*)d_out;               // [64, 8, 16]

    // 512-grid path needs (512+1)*8192 floats = 16.8 MB of workspace.
    const bool big = ws_size >= (size_t)(512 + 1) * S_ELEMS * sizeof(float);

    float* partial = (float*)d_ws;

    if (big) {
        float* vsum = partial + (size_t)512 * S_ELEMS;
        caps_pass_kernel<0, 16><<<512, 512, 0, stream>>>(x, W, vsum, partial);
        caps_reduce_kernel<0, 512><<<256, 512, 0, stream>>>(partial, vsum, nullptr);
        caps_pass_kernel<1, 16><<<512, 512, 0, stream>>>(x, W, vsum, partial);
        caps_reduce_kernel<1, 512><<<256, 512, 0, stream>>>(partial, vsum, nullptr);
        caps_pass_kernel<1, 16><<<512, 512, 0, stream>>>(x, W, vsum, partial);
        caps_reduce_kernel<2, 512><<<256, 512, 0, stream>>>(partial, vsum, out);
    } else {
        float* vsum = partial + (size_t)256 * S_ELEMS;
        caps_pass_kernel<0, 32><<<256, 512, 0, stream>>>(x, W, vsum, partial);
        caps_reduce_kernel<0, 256><<<256, 512, 0, stream>>>(partial, vsum, nullptr);
        caps_pass_kernel<1, 32><<<256, 512, 0, stream>>>(x, W, vsum, partial);
        caps_reduce_kernel<1, 256><<<256, 512, 0, stream>>>(partial, vsum, nullptr);
        caps_pass_kernel<1, 32><<<256, 512, 0, stream>>>(x, W, vsum, partial);
        caps_reduce_kernel<2, 256><<<256, 512, 0, stream>>>(partial, vsum, out);
    }
}

// Round 14
// 193.072 us; speedup vs baseline: 4.9856x; 3.5006x over previous
//
#include <hip/hip_runtime.h>

// ---------------------------------------------------------------------------
// CapsNet dynamic routing, fully fused, fp32.
//   x: [B=64, I=8192, N=8]   W: [I=8192, J=8, N=8, M=16]   out: [B, J=8, M=16]
//
// b_logits after t iters = dot(sum_{t'<=t} v_{t'}, u_hat); carry only
// vsum[B,J,M] between passes, recompute u_hat per pass (x,W are L3-resident).
//
// HW facts established over rounds 0-13 (do not re-litigate):
//   * Scheduler runs ONE workgroup per CU regardless of VGPR/LDS (r9/r10).
//     waves/CU == blockDim/64; grid 512 -> two sequential block rounds.
//   * Allocator VGPR ceiling: 128 at 512t, 64 at 1024t. The r9 pass body is
//     at the edge (120); EVERY body modification tried (x-in-LDS x3,
//     register pipelining, G-resize) hit the cliff and spilled 50-530
//     MB/pass (r7/r8/r11/r12/r13). The pass body below is r9 VERBATIM —
//     measured 45.2 us/pass, VGPR=120, zero scratch. DO NOT TOUCH.
//   * Bench accounting: r6's reduce structure gave total-minus-passes =
//     ~13 us; r7/r8/r9's deeper/runtime-loop reduces gave 40-89 us. This
//     round pairs the r9 pass with a minimal-serial-depth reduce:
//     256 x 256, 8 groups x 64 partials x 8 accumulators (depth 8),
//     compile-time unrolled, __launch_bounds__(256) like r6's.
//
// Pass layout (proven): grid 512/NCH=16, thread=(bq,j,mq) owns b in
// {bq,+16,+32,+48}; one W ds_read_b128 feeds 4b x 4m = 16 FMAs.
// WJ_STRIDE=136 -> 2-way bank overlap (free). Softmax: DPP quad_perm
// xor1/2 m-dot, row_ror:4/8 + one shfl_xor(16) j-denominator; no
// max-subtract (|logit| <~ 1). Reduce OP0 writes vsum (no memset).
// ---------------------------------------------------------------------------

#define BB      64
#define ICAPS   8192
#define NDIM    8
#define JCAPS   8
#define MDIM    16
#define IG      8                     // i's staged per barrier
#define WJ_STRIDE 136                 // 136 mod 32 = 8 -> j-rows 8 banks apart
#define WI_STRIDE (JCAPS * WJ_STRIDE) // 1088 floats per i
#define S_ELEMS  (BB * JCAPS * MDIM)  // 8192 floats per s / vsum / out

// butterfly / rotate adds on the VALU pipe via DPP.
template <int CTRL>
__device__ __forceinline__ float dpp_xadd(float v) {
    const int p = __builtin_amdgcn_mov_dpp(__float_as_int(v), CTRL, 0xF, 0xF, true);
    return v + __int_as_float(p);
}
#define DPP_XOR1 0xB1   // quad_perm [1,0,3,2]
#define DPP_XOR2 0x4E   // quad_perm [2,3,0,1]
#define DPP_ROR4 0x124  // row_ror:4
#define DPP_ROR8 0x128  // row_ror:8

// MODE 0: uniform c = 1/8 (softmax of zero logits)
// MODE 1: c = softmax_j( dot(vsum[b,j,:], u_hat[b,i,j,:]) )
// NCH: i's per block (16 for the 512-grid path, 32 for the 256 fallback)
template <int MODE, int NCH>
__global__ __launch_bounds__(512, 1)
void caps_pass_kernel(
    const float* __restrict__ x, const float* __restrict__ W,
    const float* __restrict__ vsum, float* __restrict__ partial)
{
    __shared__ float Wlds[IG * WI_STRIDE];   // 34,816 B

    const int tid = threadIdx.x;             // 0..511
    const int mq  = tid & 3;                 // m-quad (lane bits 0-1)
    const int j   = (tid >> 2) & 7;          // out-cap (lane bits 2-4)
    const int bq  = tid >> 5;                // 0..15 batch-quad base
    const int blk = blockIdx.x;
    const int i0  = blk * NCH;

    float s[4][4];                           // [b-quad][m-quad]
    #pragma unroll
    for (int k = 0; k < 4; ++k)
        #pragma unroll
        for (int m = 0; m < 4; ++m) s[k][m] = 0.f;

    float v[4][4];
    if (MODE == 1) {
        #pragma unroll
        for (int k = 0; k < 4; ++k) {
            const float4 a = *(const float4*)
                &vsum[((bq + 16 * k) * JCAPS + j) * MDIM + mq * 4];
            v[k][0] = a.x; v[k][1] = a.y; v[k][2] = a.z; v[k][3] = a.w;
        }
    }

    for (int st = 0; st < NCH / IG; ++st) {
        // ---- stage W for IG i's (each thread: 16 contiguous floats) ----
        {
            const int iL  = tid >> 6;        // 0..7
            const int rem = tid & 63;        // 16-float chunk within the i
            const float4* src = (const float4*)(W + (size_t)(i0 + st * IG + iL) * 1024
                                                  + rem * 16);
            float4* dst = (float4*)&Wlds[iL * WI_STRIDE + (rem >> 3) * WJ_STRIDE
                                         + (rem & 7) * 16];
            dst[0] = src[0]; dst[1] = src[1]; dst[2] = src[2]; dst[3] = src[3];
        }
        __syncthreads();

        #pragma unroll
        for (int ii = 0; ii < IG; ++ii) {
            const int i = i0 + st * IG + ii;

            float u[4][4];
            #pragma unroll
            for (int k = 0; k < 4; ++k)
                #pragma unroll
                for (int m = 0; m < 4; ++m) u[k][m] = 0.f;
            const float* wb = &Wlds[ii * WI_STRIDE + j * WJ_STRIDE + mq * 4];

            // n-split: keep only 16 x-floats live at a time (VGPR pressure)
            {   // n = 0..3
                float4 xa[4];
                #pragma unroll
                for (int k = 0; k < 4; ++k)
                    xa[k] = *(const float4*)&x[((size_t)(bq + 16 * k) * ICAPS + i) * NDIM];
                #pragma unroll
                for (int n = 0; n < 4; ++n) {
                    const float4 wq = *(const float4*)&wb[n * MDIM];
                    #pragma unroll
                    for (int k = 0; k < 4; ++k) {
                        const float xn = (n == 0) ? xa[k].x : (n == 1) ? xa[k].y
                                       : (n == 2) ? xa[k].z : xa[k].w;
                        u[k][0] += xn * wq.x; u[k][1] += xn * wq.y;
                        u[k][2] += xn * wq.z; u[k][3] += xn * wq.w;
                    }
                }
            }
            {   // n = 4..7
                float4 xb[4];
                #pragma unroll
                for (int k = 0; k < 4; ++k)
                    xb[k] = *(const float4*)&x[((size_t)(bq + 16 * k) * ICAPS + i) * NDIM + 4];
                #pragma unroll
                for (int n = 0; n < 4; ++n) {
                    const float4 wq = *(const float4*)&wb[(n + 4) * MDIM];
                    #pragma unroll
                    for (int k = 0; k < 4; ++k) {
                        const float xn = (n == 0) ? xb[k].x : (n == 1) ? xb[k].y
                                       : (n == 2) ? xb[k].z : xb[k].w;
                        u[k][0] += xn * wq.x; u[k][1] += xn * wq.y;
                        u[k][2] += xn * wq.z; u[k][3] += xn * wq.w;
                    }
                }
            }

            if (MODE == 0) {
                #pragma unroll
                for (int k = 0; k < 4; ++k)
                    #pragma unroll
                    for (int m = 0; m < 4; ++m) s[k][m] += u[k][m];
            } else {
                // partial logit over this m-quad (4 independent chains)
                float lp[4];
                #pragma unroll
                for (int k = 0; k < 4; ++k)
                    lp[k] = u[k][0] * v[k][0] + u[k][1] * v[k][1]
                          + u[k][2] * v[k][2] + u[k][3] * v[k][3];
                // complete m-dot across the 4 mq lanes: DPP quad_perm (VALU)
                #pragma unroll
                for (int k = 0; k < 4; ++k) lp[k] = dpp_xadd<DPP_XOR1>(lp[k]);
                #pragma unroll
                for (int k = 0; k < 4; ++k) lp[k] = dpp_xadd<DPP_XOR2>(lp[k]);
                // softmax over 8 j's: quads uniform -> row_ror:4/8 (VALU) sums
                // the 4 j's of this 16-row; one shfl_xor(16) folds the other.
                float e[4], d[4];
                #pragma unroll
                for (int k = 0; k < 4; ++k) { e[k] = __expf(lp[k]); }
                #pragma unroll
                for (int k = 0; k < 4; ++k) d[k] = dpp_xadd<DPP_ROR4>(e[k]);
                #pragma unroll
                for (int k = 0; k < 4; ++k) d[k] = dpp_xadd<DPP_ROR8>(d[k]);
                #pragma unroll
                for (int k = 0; k < 4; ++k) d[k] += __shfl_xor(d[k], 16);
                #pragma unroll
                for (int k = 0; k < 4; ++k) {
                    const float c = e[k] * __builtin_amdgcn_rcpf(d[k]);
                    #pragma unroll
                    for (int m = 0; m < 4; ++m) s[k][m] += c * u[k][m];
                }
            }
        }
        __syncthreads();
    }

    // ---- store block-partial s: partial[blk][b][j][m] (each owned once) ----
    const float sc = (MODE == 0) ? 0.125f : 1.0f;
    float* pp = partial + (size_t)blk * S_ELEMS;
    #pragma unroll
    for (int k = 0; k < 4; ++k) {
        float4 o;
        o.x = s[k][0] * sc; o.y = s[k][1] * sc;
        o.z = s[k][2] * sc; o.w = s[k][3] * sc;
        *(float4*)&pp[((bq + 16 * k) * JCAPS + j) * MDIM + mq * 4] = o;
    }
}

// Sum NPART partials -> s[b,j,m]; v = squash(s).
// 256 blocks x 256 threads (r6's proven-fast geometry, scaled): block covers
// 32 outputs; 8 groups x NPART/8 partials x 8 accumulators -> serial depth
// NPART/64 (8 at NP=512). Compile-time NPG, fully unrolled.
// OP 0: vsum = v (first pass, avoids memset)   OP 1: vsum += v   OP 2: out = v
template <int OP, int NPART>
__global__ __launch_bounds__(256) void caps_reduce_kernel(
    const float* __restrict__ partial, float* __restrict__ vsum,
    float* __restrict__ out)
{
    constexpr int NPG = NPART / 8;      // partials per group (64 or 32)
    __shared__ float sd[256];
    const int bo  = blockIdx.x;         // 0..255, each block covers 32 outputs
    const int tid = threadIdx.x;
    const int kg  = tid >> 5;           // 0..7  partial-group
    const int tl  = tid & 31;           // output-within-block (coalesced)
    const int t   = bo * 32 + tl;       // global output index (= b*128+j*16+m)

    float a0 = 0.f, a1 = 0.f, a2 = 0.f, a3 = 0.f;
    float a4 = 0.f, a5 = 0.f, a6 = 0.f, a7 = 0.f;
    const float* p = partial + (size_t)kg * NPG * S_ELEMS + t;
    #pragma unroll
    for (int k = 0; k < NPG; k += 8) {
        a0 += p[(size_t)(k + 0) * S_ELEMS];
        a1 += p[(size_t)(k + 1) * S_ELEMS];
        a2 += p[(size_t)(k + 2) * S_ELEMS];
        a3 += p[(size_t)(k + 3) * S_ELEMS];
        a4 += p[(size_t)(k + 4) * S_ELEMS];
        a5 += p[(size_t)(k + 5) * S_ELEMS];
        a6 += p[(size_t)(k + 6) * S_ELEMS];
        a7 += p[(size_t)(k + 7) * S_ELEMS];
    }
    sd[tid] = ((a0 + a1) + (a2 + a3)) + ((a4 + a5) + (a6 + a7));
    __syncthreads();

    if (tid < 32) {
        float s = 0.f;
        #pragma unroll
        for (int q = 0; q < 8; ++q) s += sd[q * 32 + tid];   // bank = tid: clean
        // squash: sn over the 16 m's of this (b,j) — lanes grouped by 16
        float sn = s * s;
        sn += __shfl_xor(sn, 1);
        sn += __shfl_xor(sn, 2);
        sn += __shfl_xor(sn, 4);
        sn += __shfl_xor(sn, 8);
        const float vv = s * sqrtf(sn) / (1.f + sn);
        const int tt = bo * 32 + tid;
        if (OP == 2)      out[tt]   = vv;
        else if (OP == 1) vsum[tt] += vv;
        else              vsum[tt]  = vv;
    }
}

extern "C" void kernel_launch(void* const* d_in, const int* in_sizes, int n_in,
                              void* d_out, int out_size, void* d_ws, size_t ws_size,
                              hipStream_t stream)
{
    const float* x = (const float*)d_in[0];   // [64, 8192, 8]
    const float* W = (const float*)d_in[1];   // [8192, 8, 8, 16]
    float* out = (float*)d_out;               // [64, 8, 16]

    // 512-grid path needs (512+1)*8192 floats = 16.8 MB of workspace.
    const bool big = ws_size >= (size_t)(512 + 1) * S_ELEMS * sizeof(float);

    float* partial = (float*)d_ws;

    if (big) {
        float* vsum = partial + (size_t)512 * S_ELEMS;
        caps_pass_kernel<0, 16><<<512, 512, 0, stream>>>(x, W, vsum, partial);
        caps_reduce_kernel<0, 512><<<256, 256, 0, stream>>>(partial, vsum, nullptr);
        caps_pass_kernel<1, 16><<<512, 512, 0, stream>>>(x, W, vsum, partial);
        caps_reduce_kernel<1, 512><<<256, 256, 0, stream>>>(partial, vsum, nullptr);
        caps_pass_kernel<1, 16><<<512, 512, 0, stream>>>(x, W, vsum, partial);
        caps_reduce_kernel<2, 512><<<256, 256, 0, stream>>>(partial, vsum, out);
    } else {
        float* vsum = partial + (size_t)256 * S_ELEMS;
        caps_pass_kernel<0, 32><<<256, 512, 0, stream>>>(x, W, vsum, partial);
        caps_reduce_kernel<0, 256><<<256, 256, 0, stream>>>(partial, vsum, nullptr);
        caps_pass_kernel<1, 32><<<256, 512, 0, stream>>>(x, W, vsum, partial);
        caps_reduce_kernel<1, 256><<<256, 256, 0, stream>>>(partial, vsum, nullptr);
        caps_pass_kernel<1, 32><<<256, 512, 0, stream>>>(x, W, vsum, partial);
        caps_reduce_kernel<2, 256><<<256, 256, 0, stream>>>(partial, vsum, out);
    }
}